// Round 3
// baseline (173.498 us; speedup 1.0000x reference)
//
#include <hip/hip_runtime.h>
#include <math.h>

// Problem constants
#define DMODEL 256
#define NSEQ   512
#define MSEQ   512

// ws layout (float offsets)
#define WS_Q      0            // [512][256]
#define WS_K      131072       // [512][256]
#define WS_V      262144       // [512][256]
#define WS_WPE    393216       // [512][256][4]  (n, d, h)
#define WS_SQK    917504       // [4][512][512]  qk part, pre-scaled
// total floats = 1966080 -> 7.5 MB

typedef float v4f __attribute__((ext_vector_type(4)));

// ---------------------------------------------------------------------------
// Kernel A: q/k/v projections.  Y = X @ W^T + b   (fp32)
// grid = 3 * 64 blocks, 256 threads (thread = out col)
// ---------------------------------------------------------------------------
__global__ __launch_bounds__(256) void proj_qkv(
    const float* __restrict__ xq, const float* __restrict__ xk,
    const float* __restrict__ xv,
    const float* __restrict__ Wq, const float* __restrict__ bq,
    const float* __restrict__ Wk, const float* __restrict__ bk,
    const float* __restrict__ Wv, const float* __restrict__ bv,
    float* __restrict__ ws)
{
    int bid = blockIdx.x;
    int mat = bid >> 6;
    int rb  = bid & 63;
    const float* X; const float* W; const float* b; float* Y;
    if (mat == 0)      { X = xq; W = Wq; b = bq; Y = ws + WS_Q; }
    else if (mat == 1) { X = xk; W = Wk; b = bk; Y = ws + WS_K; }
    else               { X = xv; W = Wv; b = bv; Y = ws + WS_V; }

    int c  = threadIdx.x;
    int r0 = rb * 8;
    float acc[8];
    float bias = b[c];
#pragma unroll
    for (int r = 0; r < 8; ++r) acc[r] = bias;

    const float4* Wrow = (const float4*)(W + (size_t)c * DMODEL);
    for (int d4 = 0; d4 < 64; ++d4) {
        float4 w = Wrow[d4];
#pragma unroll
        for (int r = 0; r < 8; ++r) {
            float4 x = ((const float4*)(X + (size_t)(r0 + r) * DMODEL))[d4];
            acc[r] += w.x * x.x + w.y * x.y + w.z * x.z + w.w * x.w;
        }
    }
#pragma unroll
    for (int r = 0; r < 8; ++r)
        Y[(size_t)(r0 + r) * DMODEL + c] = acc[r];
}

// ---------------------------------------------------------------------------
// Kernel B: W'[n][d][h] = sum_c q[n][c] * Wp[c][d]   (c = h*64+dh)
// grid = 512 blocks (1 n each), 256 threads (thread = d).
// q row staged in LDS; inner loop unrolled 8 -> 8 outstanding Wp loads.
// ---------------------------------------------------------------------------
__global__ __launch_bounds__(256) void make_wpeff(
    const float* __restrict__ Wp, float* __restrict__ ws)
{
    const float* q   = ws + WS_Q;
    float*       wpe = ws + WS_WPE;
    int n = blockIdx.x;
    int d = threadIdx.x;

    __shared__ float ql[256];
    ql[d] = q[(size_t)n * DMODEL + d];
    __syncthreads();

    float acc[4];
#pragma unroll
    for (int h = 0; h < 4; ++h) {
        float a = 0.f;
#pragma unroll 8
        for (int dh = 0; dh < 64; ++dh) {
            int c = h * 64 + dh;
            a += ql[c] * Wp[(size_t)c * DMODEL + d];
        }
        acc[h] = a;
    }
    *(float4*)&wpe[(size_t)n * 1024 + d * 4] =
        make_float4(acc[0], acc[1], acc[2], acc[3]);
}

// ---------------------------------------------------------------------------
// Kernel C: sqk[h][n][m] = 0.125 * (q[n,h]·k[m,h] + q[n,h]·bp[h])
// grid = 4h * 64 (8-n groups) = 256 blocks, 256 threads (thread = m, 2 m's).
// All LDS reads are wave-broadcast -> conflict-free.
// ---------------------------------------------------------------------------
__global__ __launch_bounds__(256) void qk_scores(
    const float* __restrict__ bp, float* __restrict__ ws)
{
    const float* q   = ws + WS_Q;
    const float* k   = ws + WS_K;
    float*       sqk = ws + WS_SQK;

    int bid = blockIdx.x;
    int h   = bid >> 6;
    int g   = bid & 63;
    int n0  = g * 8;
    int tid = threadIdx.x;

    __shared__ float qls[8][64];
    __shared__ float qb[8];

    if (tid < 128) {
        int row = tid >> 4, col = (tid & 15) * 4;
        *(float4*)&qls[row][col] =
            *(const float4*)&q[(size_t)(n0 + row) * DMODEL + h * 64 + col];
    }
    __syncthreads();
    if (tid < 8) {
        float s = 0.f;
        for (int dh = 0; dh < 64; ++dh) s += qls[tid][dh] * bp[h * 64 + dh];
        qb[tid] = s;
    }
    __syncthreads();

    const float* ka = k + (size_t)tid * DMODEL + h * 64;
    const float* kb = ka + (size_t)256 * DMODEL;
    float acca[8] = {};
    float accb[8] = {};
#pragma unroll 4
    for (int d4 = 0; d4 < 16; ++d4) {
        float4 xa = *(const float4*)(ka + d4 * 4);
        float4 xb = *(const float4*)(kb + d4 * 4);
#pragma unroll
        for (int j = 0; j < 8; ++j) {
            float4 qq = *(const float4*)&qls[j][d4 * 4];
            acca[j] += xa.x * qq.x + xa.y * qq.y + xa.z * qq.z + xa.w * qq.w;
            accb[j] += xb.x * qq.x + xb.y * qq.y + xb.z * qq.z + xb.w * qq.w;
        }
    }
#pragma unroll
    for (int j = 0; j < 8; ++j) {
        size_t base = (size_t)h * 262144 + (size_t)(n0 + j) * MSEQ;
        sqk[base + tid]       = 0.125f * (acca[j] + qb[j]);
        sqk[base + tid + 256] = 0.125f * (accb[j] + qb[j]);
    }
}

// ---------------------------------------------------------------------------
// Kernel D (fused): per n-row -- stream input_p (nontemporal), add qk scores,
// masked softmax over m (block reduction), attn @ v, write out row.
// grid = 512 blocks (1 n each), 512 threads (thread = m).  Scores never
// touch HBM.
// ---------------------------------------------------------------------------
__global__ __launch_bounds__(512) void fused_attn(
    const float* __restrict__ Xp, const unsigned char* __restrict__ mask,
    float* __restrict__ out, float* __restrict__ ws)
{
    const float* wpe = ws + WS_WPE;
    const float* v   = ws + WS_V;
    const float* sqk = ws + WS_SQK;

    int n    = blockIdx.x;
    int tid  = threadIdx.x;          // = m
    int lane = tid & 63, wv = tid >> 6;

    __shared__ float4 wl[256];       // W'[n]  4 KB
    __shared__ float4 sc[512];       // attn   8 KB
    __shared__ float4 wredm[8];
    __shared__ float4 wreds[8];
    __shared__ float  red[256];

    if (tid < 256)
        wl[tid] = *(const float4*)&wpe[(size_t)n * 1024 + tid * 4];
    __syncthreads();

    // ---- stream this thread's input_p row (1 KB), dot with W' ----
    const v4f* xrow = (const v4f*)(Xp + ((size_t)n * MSEQ + tid) * DMODEL);
    float s0 = 0.f, s1 = 0.f, s2 = 0.f, s3 = 0.f;
#pragma unroll 8
    for (int d4 = 0; d4 < 64; ++d4) {
        v4f x = __builtin_nontemporal_load(&xrow[d4]);
        float4 w0 = wl[d4 * 4 + 0];
        float4 w1 = wl[d4 * 4 + 1];
        float4 w2 = wl[d4 * 4 + 2];
        float4 w3 = wl[d4 * 4 + 3];
        s0 += x.x * w0.x + x.y * w1.x + x.z * w2.x + x.w * w3.x;
        s1 += x.x * w0.y + x.y * w1.y + x.z * w2.y + x.w * w3.y;
        s2 += x.x * w0.z + x.y * w1.z + x.z * w2.z + x.w * w3.z;
        s3 += x.x * w0.w + x.y * w1.w + x.z * w2.w + x.w * w3.w;
    }

    size_t ob = (size_t)n * MSEQ + tid;
    float s[4];
    s[0] = sqk[0 * 262144 + ob] + 0.125f * s0;
    s[1] = sqk[1 * 262144 + ob] + 0.125f * s1;
    s[2] = sqk[2 * 262144 + ob] + 0.125f * s2;
    s[3] = sqk[3 * 262144 + ob] + 0.125f * s3;
    if (mask[tid]) { s[0] = s[1] = s[2] = s[3] = -INFINITY; }

    // ---- block max per head ----
    float mx[4] = { s[0], s[1], s[2], s[3] };
#pragma unroll
    for (int off = 32; off; off >>= 1) {
#pragma unroll
        for (int h = 0; h < 4; ++h) mx[h] = fmaxf(mx[h], __shfl_xor(mx[h], off));
    }
    if (lane == 0) wredm[wv] = make_float4(mx[0], mx[1], mx[2], mx[3]);
    __syncthreads();
    float4 M = wredm[0];
#pragma unroll
    for (int w = 1; w < 8; ++w) {
        float4 t = wredm[w];
        M.x = fmaxf(M.x, t.x); M.y = fmaxf(M.y, t.y);
        M.z = fmaxf(M.z, t.z); M.w = fmaxf(M.w, t.w);
    }

    // ---- exp + block sum per head ----
    float e[4];
    e[0] = __expf(s[0] - M.x); e[1] = __expf(s[1] - M.y);
    e[2] = __expf(s[2] - M.z); e[3] = __expf(s[3] - M.w);
    float sm[4] = { e[0], e[1], e[2], e[3] };
#pragma unroll
    for (int off = 32; off; off >>= 1) {
#pragma unroll
        for (int h = 0; h < 4; ++h) sm[h] += __shfl_xor(sm[h], off);
    }
    if (lane == 0) wreds[wv] = make_float4(sm[0], sm[1], sm[2], sm[3]);
    __syncthreads();
    float4 S = wreds[0];
#pragma unroll
    for (int w = 1; w < 8; ++w) {
        float4 t = wreds[w];
        S.x += t.x; S.y += t.y; S.z += t.z; S.w += t.w;
    }

    sc[tid] = make_float4(e[0] * (1.f / S.x), e[1] * (1.f / S.y),
                          e[2] * (1.f / S.z), e[3] * (1.f / S.w));
    __syncthreads();

    // ---- AV: thread = (col c, m-half); attn broadcast from LDS ----
    int c = tid & 255, half = tid >> 8;
    int hh = c >> 6;
    const float* vcol = v + c;
    float acc = 0.f;
#pragma unroll 8
    for (int i = 0; i < 256; ++i) {
        int m = half * 256 + i;
        acc += ((const float*)&sc[m])[hh] * vcol[(size_t)m * DMODEL];
    }
    if (half) red[c] = acc;
    __syncthreads();
    if (!half) out[(size_t)n * DMODEL + c] = acc + red[c];
}

// ---------------------------------------------------------------------------
extern "C" void kernel_launch(void* const* d_in, const int* in_sizes, int n_in,
                              void* d_out, int out_size, void* d_ws,
                              size_t ws_size, hipStream_t stream)
{
    const float* xq = (const float*)d_in[0];
    const float* xk = (const float*)d_in[1];
    const float* xv = (const float*)d_in[2];
    const float* xp = (const float*)d_in[3];
    const unsigned char* mask = (const unsigned char*)d_in[4];
    const float* Wq = (const float*)d_in[5];
    const float* bq = (const float*)d_in[6];
    const float* Wk = (const float*)d_in[7];
    const float* bk = (const float*)d_in[8];
    const float* Wv = (const float*)d_in[9];
    const float* bv = (const float*)d_in[10];
    const float* Wp = (const float*)d_in[11];
    const float* bp = (const float*)d_in[12];
    float* out = (float*)d_out;
    float* ws  = (float*)d_ws;

    proj_qkv  <<<192, 256, 0, stream>>>(xq, xk, xv, Wq, bq, Wk, bk, Wv, bv, ws);
    make_wpeff<<<512, 256, 0, stream>>>(Wp, ws);
    qk_scores <<<256, 256, 0, stream>>>(bp, ws);
    fused_attn<<<512, 512, 0, stream>>>(xp, mask, out, ws);
}

// Round 4
// 107.897 us; speedup vs baseline: 1.6080x; 1.6080x over previous
//
#include <hip/hip_runtime.h>
#include <math.h>

// Problem constants
#define DMODEL 256
#define NSEQ   512
#define MSEQ   512

// ws layout (float offsets)
#define WS_Q      0            // [512][256]
#define WS_K      131072       // [512][256]
#define WS_V      262144       // [512][256]
#define WS_WPE    393216       // [512][256][4]  (n, d, h)
#define WS_SQK    917504       // [4][512][512]  qk part prescaled, then final scores (in-place)
// total floats = 1966080 -> 7.5 MB

typedef float v4f __attribute__((ext_vector_type(4)));

// ---------------------------------------------------------------------------
// Kernel A: q/k/v projections.  Y = X @ W^T + b   (fp32)
// grid = 3 * 64 blocks, 256 threads (thread = out col)
// ---------------------------------------------------------------------------
__global__ __launch_bounds__(256) void proj_qkv(
    const float* __restrict__ xq, const float* __restrict__ xk,
    const float* __restrict__ xv,
    const float* __restrict__ Wq, const float* __restrict__ bq,
    const float* __restrict__ Wk, const float* __restrict__ bk,
    const float* __restrict__ Wv, const float* __restrict__ bv,
    float* __restrict__ ws)
{
    int bid = blockIdx.x;
    int mat = bid >> 6;
    int rb  = bid & 63;
    const float* X; const float* W; const float* b; float* Y;
    if (mat == 0)      { X = xq; W = Wq; b = bq; Y = ws + WS_Q; }
    else if (mat == 1) { X = xk; W = Wk; b = bk; Y = ws + WS_K; }
    else               { X = xv; W = Wv; b = bv; Y = ws + WS_V; }

    int c  = threadIdx.x;
    int r0 = rb * 8;
    float acc[8];
    float bias = b[c];
#pragma unroll
    for (int r = 0; r < 8; ++r) acc[r] = bias;

    const float4* Wrow = (const float4*)(W + (size_t)c * DMODEL);
    for (int d4 = 0; d4 < 64; ++d4) {
        float4 w = Wrow[d4];
#pragma unroll
        for (int r = 0; r < 8; ++r) {
            float4 x = ((const float4*)(X + (size_t)(r0 + r) * DMODEL))[d4];
            acc[r] += w.x * x.x + w.y * x.y + w.z * x.z + w.w * x.w;
        }
    }
#pragma unroll
    for (int r = 0; r < 8; ++r)
        Y[(size_t)(r0 + r) * DMODEL + c] = acc[r];
}

// ---------------------------------------------------------------------------
// Kernel B: W'[n][d][h] = sum_c q[n][c] * Wp[c][d]
// grid = 512 blocks (1 n each), 256 threads (thread = d).
// ---------------------------------------------------------------------------
__global__ __launch_bounds__(256) void make_wpeff(
    const float* __restrict__ Wp, float* __restrict__ ws)
{
    const float* q   = ws + WS_Q;
    float*       wpe = ws + WS_WPE;
    int n = blockIdx.x;
    int d = threadIdx.x;

    __shared__ float ql[256];
    ql[d] = q[(size_t)n * DMODEL + d];
    __syncthreads();

    float acc[4];
#pragma unroll
    for (int h = 0; h < 4; ++h) {
        float a = 0.f;
#pragma unroll 8
        for (int dh = 0; dh < 64; ++dh) {
            int c = h * 64 + dh;
            a += ql[c] * Wp[(size_t)c * DMODEL + d];
        }
        acc[h] = a;
    }
    *(float4*)&wpe[(size_t)n * 1024 + d * 4] =
        make_float4(acc[0], acc[1], acc[2], acc[3]);
}

// ---------------------------------------------------------------------------
// Kernel C: sqk[h][n][m] = 0.125 * (q[n,h]·k[m,h] + q[n,h]·bp[h])
// grid = 256 blocks (h, 8-n group), 256 threads. Write-only (no rmw).
// ---------------------------------------------------------------------------
__global__ __launch_bounds__(256) void qk_scores(
    const float* __restrict__ bp, float* __restrict__ ws)
{
    const float* q   = ws + WS_Q;
    const float* k   = ws + WS_K;
    float*       sqk = ws + WS_SQK;

    int bid = blockIdx.x;
    int h   = bid >> 6;
    int g   = bid & 63;
    int n0  = g * 8;
    int tid = threadIdx.x;

    __shared__ float qls[8][64];
    __shared__ float qb[8];

    if (tid < 128) {
        int row = tid >> 4, col = (tid & 15) * 4;
        *(float4*)&qls[row][col] =
            *(const float4*)&q[(size_t)(n0 + row) * DMODEL + h * 64 + col];
    }
    __syncthreads();
    if (tid < 8) {
        float s = 0.f;
        for (int dh = 0; dh < 64; ++dh) s += qls[tid][dh] * bp[h * 64 + dh];
        qb[tid] = s;
    }
    __syncthreads();

    const float* ka = k + (size_t)tid * DMODEL + h * 64;
    const float* kb = ka + (size_t)256 * DMODEL;
    float acca[8] = {};
    float accb[8] = {};
#pragma unroll 4
    for (int d4 = 0; d4 < 16; ++d4) {
        float4 xa = *(const float4*)(ka + d4 * 4);
        float4 xb = *(const float4*)(kb + d4 * 4);
#pragma unroll
        for (int j = 0; j < 8; ++j) {
            float4 qq = *(const float4*)&qls[j][d4 * 4];
            acca[j] += xa.x * qq.x + xa.y * qq.y + xa.z * qq.z + xa.w * qq.w;
            accb[j] += xb.x * qq.x + xb.y * qq.y + xb.z * qq.z + xb.w * qq.w;
        }
    }
#pragma unroll
    for (int j = 0; j < 8; ++j) {
        size_t base = (size_t)h * 262144 + (size_t)(n0 + j) * MSEQ;
        sqk[base + tid]       = 0.125f * (acca[j] + qb[j]);
        sqk[base + tid + 256] = 0.125f * (accb[j] + qb[j]);
    }
}

// ---------------------------------------------------------------------------
// Kernel D: HBM-streaming kernel. Coalesced (4 x 256B contiguous per load
// instruction, every line fully consumed per instruction -> NT-safe) with
// NONTEMPORAL loads to avoid L3 write-allocate on the 268 MB one-shot stream.
// Epilogue adds prescaled qk scores in-place: sqk <- sqk + 0.125 * (p . W').
// grid = 1024 blocks (n, m-half of 256 rows), 256 threads (4 waves).
// ---------------------------------------------------------------------------
__global__ __launch_bounds__(256) void p_scores(
    const float* __restrict__ Xp, float* __restrict__ ws)
{
    const float* wpe = ws + WS_WPE;
    float*       sqk = ws + WS_SQK;

    int bid  = blockIdx.x;
    int n    = bid >> 1;
    int m0   = (bid & 1) * 256;
    int tid  = threadIdx.x;
    int wv   = tid >> 6;
    int lane = tid & 63;
    int p    = lane & 15;         // d-slice within row
    int r3   = lane >> 4;         // row within group of 4

    // W' for this lane's d-slice: float4 w[j][c] covers d = 4p + 64j + c
    const float4* wp4 = (const float4*)(wpe + (size_t)n * 1024);
    float4 w[4][4];
#pragma unroll
    for (int j = 0; j < 4; ++j)
#pragma unroll
        for (int c = 0; c < 4; ++c)
            w[j][c] = wp4[4 * p + 64 * j + c];

    __shared__ float sm[4][256];

    const v4f* base4 =
        (const v4f*)Xp + ((size_t)n * MSEQ + m0 + wv * 64) * 64;

#pragma unroll 2
    for (int g = 0; g < 16; ++g) {
        int rbase = (g * 4 + r3) * 64 + p;
        v4f xv0 = __builtin_nontemporal_load(&base4[rbase + 0]);
        v4f xv1 = __builtin_nontemporal_load(&base4[rbase + 16]);
        v4f xv2 = __builtin_nontemporal_load(&base4[rbase + 32]);
        v4f xv3 = __builtin_nontemporal_load(&base4[rbase + 48]);

        float sh[4] = {0.f, 0.f, 0.f, 0.f};
        {
            const v4f xs[4] = {xv0, xv1, xv2, xv3};
#pragma unroll
            for (int j = 0; j < 4; ++j) {
#pragma unroll
                for (int c = 0; c < 4; ++c) {
                    const float xc = xs[j][c];
                    const float* wf = &w[j][c].x;
#pragma unroll
                    for (int h = 0; h < 4; ++h)
                        sh[h] += xc * wf[h];
                }
            }
        }
        // reduce over the 16 lanes of this row
#pragma unroll
        for (int off = 1; off < 16; off <<= 1) {
#pragma unroll
            for (int h = 0; h < 4; ++h)
                sh[h] += __shfl_xor(sh[h], off);
        }
        if (p == 0) {
            int ml = wv * 64 + g * 4 + r3;
            sm[0][ml] = sh[0];
            sm[1][ml] = sh[1];
            sm[2][ml] = sh[2];
            sm[3][ml] = sh[3];
        }
    }
    __syncthreads();

    size_t ob = (size_t)n * MSEQ + m0 + tid;
#pragma unroll
    for (int h = 0; h < 4; ++h)
        sqk[h * 262144 + ob] += 0.125f * sm[h][tid];
}

// ---------------------------------------------------------------------------
// Kernel E: masked softmax over m + attn @ v, writes final output.
// (round-1 version verbatim; reads final scores from the sqk buffer)
// ---------------------------------------------------------------------------
__global__ __launch_bounds__(256) void softmax_av(
    const unsigned char* __restrict__ mask,
    float* __restrict__ out, float* __restrict__ ws)
{
    const float* v      = ws + WS_V;
    const float* scores = ws + WS_SQK;

    int bid = blockIdx.x;
    int h   = bid >> 6;
    int g   = bid & 63;
    int n0  = g * 8;

    __shared__ float  pl[MSEQ * 8];   // [m][j]  16 KB
    __shared__ float4 red4[256];      // reduce scratch 4 KB
    __shared__ float  wred[4];

    int tid  = threadIdx.x;
    int lane = tid & 63, wv = tid >> 6;

    for (int j = 0; j < 8; ++j) {
        int n = n0 + j;
        const float* srow = scores + (size_t)h * 262144 + (size_t)n * MSEQ;
        float s0 = srow[tid];
        float s1 = srow[tid + 256];
        if (mask[tid])       s0 = -INFINITY;
        if (mask[tid + 256]) s1 = -INFINITY;

        float mx = fmaxf(s0, s1);
#pragma unroll
        for (int off = 32; off; off >>= 1) mx = fmaxf(mx, __shfl_xor(mx, off));
        if (lane == 0) wred[wv] = mx;
        __syncthreads();
        mx = fmaxf(fmaxf(wred[0], wred[1]), fmaxf(wred[2], wred[3]));

        float e0 = __expf(s0 - mx);
        float e1 = __expf(s1 - mx);
        float sm = e0 + e1;
#pragma unroll
        for (int off = 32; off; off >>= 1) sm += __shfl_xor(sm, off);
        __syncthreads();
        if (lane == 0) wred[wv] = sm;
        __syncthreads();
        sm = wred[0] + wred[1] + wred[2] + wred[3];
        float rinv = 1.0f / sm;

        pl[(size_t)tid * 8 + j]         = e0 * rinv;
        pl[(size_t)(tid + 256) * 8 + j] = e1 * rinv;
        __syncthreads();
    }

    // AV: thread = (dhq 0..15, mq 0..15); each covers 32 m values.
    int dhq = tid & 15, mq = tid >> 4;
    float acc[8][4] = {};
    for (int i = 0; i < 32; ++i) {
        int m = mq * 32 + i;
        float4 vv = *(const float4*)&v[(size_t)m * DMODEL + h * 64 + dhq * 4];
        float4 pa = *(const float4*)&pl[m * 8];
        float4 pb = *(const float4*)&pl[m * 8 + 4];
#pragma unroll
        for (int j = 0; j < 4; ++j) {
            float pv = (&pa.x)[j];
            acc[j][0] += pv * vv.x; acc[j][1] += pv * vv.y;
            acc[j][2] += pv * vv.z; acc[j][3] += pv * vv.w;
        }
#pragma unroll
        for (int j = 0; j < 4; ++j) {
            float pv = (&pb.x)[j];
            acc[4 + j][0] += pv * vv.x; acc[4 + j][1] += pv * vv.y;
            acc[4 + j][2] += pv * vv.z; acc[4 + j][3] += pv * vv.w;
        }
    }

    for (int j = 0; j < 8; ++j) {
        red4[mq * 16 + dhq] =
            make_float4(acc[j][0], acc[j][1], acc[j][2], acc[j][3]);
        __syncthreads();
        if (tid < 64) {
            int dq = tid >> 2, x = tid & 3;
            float s = 0.f;
#pragma unroll
            for (int qq = 0; qq < 16; ++qq)
                s += ((const float*)&red4[qq * 16 + dq])[x];
            out[(size_t)(n0 + j) * DMODEL + h * 64 + tid] = s;
        }
        __syncthreads();
    }
}

// ---------------------------------------------------------------------------
extern "C" void kernel_launch(void* const* d_in, const int* in_sizes, int n_in,
                              void* d_out, int out_size, void* d_ws,
                              size_t ws_size, hipStream_t stream)
{
    const float* xq = (const float*)d_in[0];
    const float* xk = (const float*)d_in[1];
    const float* xv = (const float*)d_in[2];
    const float* xp = (const float*)d_in[3];
    const unsigned char* mask = (const unsigned char*)d_in[4];
    const float* Wq = (const float*)d_in[5];
    const float* bq = (const float*)d_in[6];
    const float* Wk = (const float*)d_in[7];
    const float* bk = (const float*)d_in[8];
    const float* Wv = (const float*)d_in[9];
    const float* bv = (const float*)d_in[10];
    const float* Wp = (const float*)d_in[11];
    const float* bp = (const float*)d_in[12];
    float* out = (float*)d_out;
    float* ws  = (float*)d_ws;

    proj_qkv  <<<192,  256, 0, stream>>>(xq, xk, xv, Wq, bq, Wk, bk, Wv, bv, ws);
    make_wpeff<<<512,  256, 0, stream>>>(Wp, ws);
    qk_scores <<<256,  256, 0, stream>>>(bp, ws);
    p_scores  <<<1024, 256, 0, stream>>>(xp, ws);
    softmax_av<<<256,  256, 0, stream>>>(mask, out, ws);
}